// Round 16
// baseline (4699.107 us; speedup 1.0000x reference)
//
#include <hip/hip_runtime.h>
#include <hip/hip_bf16.h>
#include <hip/hip_fp16.h>

// Problem constants
#define NB 32
#define TO 64
#define TT 65
#define TI 512
#define VV 10000
#define HH 512
#define G4 2048
#define SOS_ID 1
#define EOS_ID 2
#define NBLK 256

typedef unsigned uvec4 __attribute__((ext_vector_type(4)));
typedef unsigned uvec2 __attribute__((ext_vector_type(2)));
typedef short bf16x4 __attribute__((ext_vector_type(4)));
typedef short bf16x8 __attribute__((ext_vector_type(8)));
typedef float f32x4 __attribute__((ext_vector_type(4)));

__device__ __forceinline__ float cload1(const float* p) {
    unsigned v = __hip_atomic_load((const unsigned*)p,
                                   __ATOMIC_RELAXED, __HIP_MEMORY_SCOPE_AGENT);
    return __uint_as_float(v);
}
__device__ __forceinline__ float2 cload2(const float* p) {
    unsigned long long v = __hip_atomic_load((const unsigned long long*)p,
                                             __ATOMIC_RELAXED, __HIP_MEMORY_SCOPE_AGENT);
    float2 r;
    r.x = __uint_as_float((unsigned)(v & 0xffffffffull));
    r.y = __uint_as_float((unsigned)(v >> 32));
    return r;
}
__device__ __forceinline__ void cstore(float* p, float v) {
    __hip_atomic_store((unsigned*)p, __float_as_uint(v),
                       __ATOMIC_RELAXED, __HIP_MEMORY_SCOPE_AGENT);
}

// Split group barrier. arrive: drain + block-sync + flag store.
// wait: poll all 32 slice flags of the group, then block-sync.
// Alternating two groups per block keeps each wait "hot" (flags set during
// the other group's compute), so polls terminate in ~1 iteration.
__device__ __forceinline__ void garrive(int* flags, int gid, int s, int& ep) {
    asm volatile("s_waitcnt vmcnt(0) lgkmcnt(0)" ::: "memory");
    __syncthreads();
    ep++;
    if (threadIdx.x == 0)
        __hip_atomic_store(&flags[(gid * 32 + s) * 16], ep,
                           __ATOMIC_RELAXED, __HIP_MEMORY_SCOPE_AGENT);
}
__device__ __forceinline__ void gwait(int* flags, int gid, int ep) {
    if (threadIdx.x < 32) {
        for (;;) {
            int v = __hip_atomic_load(&flags[(gid * 32 + (int)threadIdx.x) * 16],
                                      __ATOMIC_RELAXED, __HIP_MEMORY_SCOPE_AGENT);
            unsigned long long b = __ballot(v >= ep);
            if ((b & 0xffffffffull) == 0xffffffffull) break;
            __builtin_amdgcn_s_sleep(1);
        }
    }
    __syncthreads();
}

__device__ __forceinline__ float bf2f(unsigned u16) {
    return __uint_as_float(u16 << 16);
}
__device__ __forceinline__ unsigned f2bf(float f) {
    unsigned u = __float_as_uint(f);
    return (u + 0x7fffu + ((u >> 16) & 1u)) >> 16;
}
__device__ __forceinline__ unsigned packbf2(float a, float b) {
    return f2bf(a) | (f2bf(b) << 16);
}

// ---------------------------------------------------------------------------
// LSTM gemm+gate for a 2-row group: 16-wave k-split, quad-packed bf16 weights
// (layout identical to r11-15). xs2[k] = (x[row0], x[row1]).
// ---------------------------------------------------------------------------
template <int KQ4>  // quads per wave: 24 (L0) or 16 (L1,L2)
__device__ __forceinline__ void lstm_gemm_gate(
    const unsigned* __restrict__ Wtb, const float* __restrict__ bi,
    const float* __restrict__ bh, float* __restrict__ hout,
    float& creg, float* __restrict__ mlprow,
    const float2* xs2, float* sg, float* sg2, int s, int n0) {
    int tid = threadIdx.x;
    int lane = tid & 63, wv = tid >> 6;
    const uvec2* wp = (const uvec2*)Wtb + (long)(wv * KQ4) * 2048 + (s * 64 + lane);
    const float2* xp = xs2 + wv * KQ4 * 4;
    float a0 = 0.f, a1 = 0.f;
#pragma unroll 4
    for (int kq = 0; kq < KQ4; kq++) {
        uvec2 u = wp[(long)kq * 2048];
        float w0 = bf2f(u.x & 0xffffu), w1 = bf2f(u.x >> 16);
        float w2 = bf2f(u.y & 0xffffu), w3 = bf2f(u.y >> 16);
        float2 x0 = xp[4 * kq], x1 = xp[4 * kq + 1];
        float2 x2 = xp[4 * kq + 2], x3 = xp[4 * kq + 3];
        a0 = fmaf(w0, x0.x, a0); a1 = fmaf(w0, x0.y, a1);
        a0 = fmaf(w1, x1.x, a0); a1 = fmaf(w1, x1.y, a1);
        a0 = fmaf(w2, x2.x, a0); a1 = fmaf(w2, x2.y, a1);
        a0 = fmaf(w3, x3.x, a0); a1 = fmaf(w3, x3.y, a1);
    }
    float2 r2; r2.x = a0; r2.y = a1;
    ((float2*)sg)[wv * 64 + lane] = r2;
    __syncthreads();
    if (tid < 512) {   // first-level reduce: (c 64, n 2, w4 4)
        int c = tid >> 3, n = (tid >> 2) & 1, w4 = tid & 3;
        float sum = sg[((w4 * 4 + 0) * 64 + c) * 2 + n]
                  + sg[((w4 * 4 + 1) * 64 + c) * 2 + n]
                  + sg[((w4 * 4 + 2) * 64 + c) * 2 + n]
                  + sg[((w4 * 4 + 3) * 64 + c) * 2 + n];
        sg2[c * 8 + n * 4 + w4] = sum;
    }
    __syncthreads();
    if (tid < 32) {
        int n = tid >> 4, ml = tid & 15, gm = s * 16 + ml;
        float ga[4];
#pragma unroll
        for (int q = 0; q < 4; q++) {
            const float* p = sg2 + (q * 16 + ml) * 8 + n * 4;
            ga[q] = p[0] + p[1] + p[2] + p[3];
        }
        float gi = ga[0] + bi[gm] + bh[gm];
        float gf = ga[1] + bi[512 + gm] + bh[512 + gm];
        float gg = ga[2] + bi[1024 + gm] + bh[1024 + gm];
        float go = ga[3] + bi[1536 + gm] + bh[1536 + gm];
        float si = 1.f / (1.f + expf(-gi));
        float sf = 1.f / (1.f + expf(-gf));
        float so = 1.f / (1.f + expf(-go));
        float c2 = sf * creg + si * tanhf(gg);
        creg = c2;
        float hv = so * tanhf(c2);
        cstore(&hout[(n0 + n) * 512 + gm], hv);
        if (mlprow) mlprow[(long)(n0 + n) * 1024 + gm] = hv;
    }
}

// ---------------------------------------------------------------------------
// P1: stage x=[emb|att(combined)|h0r] and run L0. t>0 path combines the 16
// attention partials (exact online-softmax algebra) written at P45(t-1).
// ---------------------------------------------------------------------------
__device__ __forceinline__ void phase1(
    const unsigned* __restrict__ Wtb0, const float* __restrict__ b_ih0,
    const float* __restrict__ b_hh0, const float* __restrict__ emb,
    const int* __restrict__ tokens, int t,
    const float* __restrict__ h0r, float* __restrict__ h0w, float& c0,
    float* __restrict__ pvec, float* __restrict__ pm, float* __restrict__ mlpin,
    float2* xs2, float* sg, float* sg2, int s, int n0) {
    int tid = threadIdx.x;
    if (t == 0) {
        if (tid < 768) {
            int k = tid * 2;
            float2 v0, v1;
            if (k < 512) {
                float2 e = *(const float2*)(emb + (long)SOS_ID * 512 + k);
                v0.x = e.x; v0.y = e.x; v1.x = e.y; v1.y = e.y;
            } else {
                v0.x = v0.y = v1.x = v1.y = 0.f;
            }
            xs2[k] = v0; xs2[k + 1] = v1;
        }
        __syncthreads();
    } else {
        int r0 = tokens[(n0 + 0) * TO + t - 1];
        int r1 = tokens[(n0 + 1) * TO + t - 1];
        if (tid < 32) {          // stage (m,d) pairs for both rows
            int nn = tid >> 4, bb = tid & 15;
            float2 md = cload2(&pm[((n0 + nn) * 16 + bb) * 2]);
            sg[2048 + (nn * 16 + bb) * 2] = md.x;
            sg[2048 + (nn * 16 + bb) * 2 + 1] = md.y;
        } else if (tid >= 512) {  // stage emb + h0r concurrently
            int idx = tid - 512;
            if (idx < 256) {
                int k = idx * 2;
                float2 ea = *(const float2*)(emb + (long)r0 * 512 + k);
                float2 eb = *(const float2*)(emb + (long)r1 * 512 + k);
                float2 v0, v1;
                v0.x = ea.x; v0.y = eb.x; v1.x = ea.y; v1.y = eb.y;
                xs2[k] = v0; xs2[k + 1] = v1;
            } else {
                int k = (idx - 256) * 2;
                float2 ha = cload2(h0r + (n0 + 0) * 512 + k);
                float2 hb = cload2(h0r + (n0 + 1) * 512 + k);
                float2 v0, v1;
                v0.x = ha.x; v0.y = hb.x; v1.x = ha.y; v1.y = hb.y;
                xs2[1024 + k] = v0; xs2[1024 + k + 1] = v1;
            }
        }
        __syncthreads();
        if (tid < 512) {          // combine 16 partials, write att rows to LDS
            int nn = tid >> 8, hp = (tid & 255) * 2;
            float M = -1e30f;
#pragma unroll
            for (int bb = 0; bb < 16; bb++)
                M = fmaxf(M, sg[2048 + (nn * 16 + bb) * 2]);
            float al[16], den = 0.f;
#pragma unroll
            for (int bb = 0; bb < 16; bb++) {
                al[bb] = expf(sg[2048 + (nn * 16 + bb) * 2] - M);
                den += al[bb] * sg[2048 + (nn * 16 + bb) * 2 + 1];
            }
            float inv = 1.f / den;
            float a0 = 0.f, a1 = 0.f;
#pragma unroll
            for (int bb = 0; bb < 16; bb++) {
                float c = al[bb] * inv;
                float2 v = cload2(&pvec[((long)(n0 + nn) * 16 + bb) * 512 + hp]);
                a0 = fmaf(c, v.x, a0);
                a1 = fmaf(c, v.y, a1);
            }
            sg[1024 + nn * 512 + hp] = a0;
            sg[1024 + nn * 512 + hp + 1] = a1;
            if ((hp >> 4) == s) {  // exactly-one-block writer for mlpin att-half
                float* mp = mlpin + ((long)(t - 1) * NB + (n0 + nn)) * 1024 + 512 + hp;
                mp[0] = a0; mp[1] = a1;
            }
        }
        __syncthreads();
        if (tid < 512) {          // transpose att rows into xs2
            float2 v;
            v.x = sg[1024 + tid];
            v.y = sg[1536 + tid];
            xs2[512 + tid] = v;
        }
        __syncthreads();
    }
    lstm_gemm_gate<24>(Wtb0, b_ih0, b_hh0, h0w, c0, nullptr, xs2, sg, sg2, s, n0);
}

// P2/P3: x = [hdep | hind]
__device__ __forceinline__ void phase23(
    const unsigned* __restrict__ Wtb, const float* __restrict__ bi,
    const float* __restrict__ bh, const float* __restrict__ hdep,
    const float* __restrict__ hind, float* __restrict__ hout, float& creg,
    float* __restrict__ mlprow, float2* xs2, float* sg, float* sg2,
    int s, int n0) {
    int tid = threadIdx.x;
    if (tid < 512) {
        int k = tid * 2;
        const float* b0;
        const float* b1;
        int kk;
        if (k < 512) { b0 = hdep + (n0 + 0) * 512; b1 = hdep + (n0 + 1) * 512; kk = k; }
        else { b0 = hind + (n0 + 0) * 512; b1 = hind + (n0 + 1) * 512; kk = k - 512; }
        float2 a = cload2(b0 + kk), b2 = cload2(b1 + kk);
        float2 v0, v1;
        v0.x = a.x; v0.y = b2.x; v1.x = a.y; v1.y = b2.y;
        xs2[k] = v0; xs2[k + 1] = v1;
    }
    __syncthreads();
    lstm_gemm_gate<16>(Wtb, bi, bh, hout, creg, mlprow, xs2, sg, sg2, s, n0);
}

// P45: scores over the 32-ti LDS tile + tile-local softmax + partial apply.
__device__ __forceinline__ void phase45(
    const unsigned short* __restrict__ enct, const float* __restrict__ h2w,
    int na, int tiq, float* __restrict__ pvec, float* __restrict__ pm,
    float* sg, float* sg2, float* wl) {
    int tid = threadIdx.x;
    if (tid < 512) sg2[tid] = cload1(h2w + na * 512 + tid);
    __syncthreads();
    {
        int tl = tid & 31, kh = tid >> 5;   // 32 ti x 32 kh-groups (16 h each)
        float acc = 0.f;
#pragma unroll
        for (int q = 0; q < 2; q++) {
            int gg = kh * 2 + q;
            uvec4 e = *(const uvec4*)(enct + tl * 512 + ((gg ^ (tl & 7)) * 8));
            const float* hp = sg2 + gg * 8;
            acc += bf2f(e.x & 0xffffu) * hp[0] + bf2f(e.x >> 16) * hp[1]
                 + bf2f(e.y & 0xffffu) * hp[2] + bf2f(e.y >> 16) * hp[3]
                 + bf2f(e.z & 0xffffu) * hp[4] + bf2f(e.z >> 16) * hp[5]
                 + bf2f(e.w & 0xffffu) * hp[6] + bf2f(e.w >> 16) * hp[7];
        }
        sg[kh * 32 + tl] = acc;
    }
    __syncthreads();
    if (tid < 256) {
        int tl = tid & 31, k8 = tid >> 5;
        float sv = sg[(k8 * 4 + 0) * 32 + tl] + sg[(k8 * 4 + 1) * 32 + tl]
                 + sg[(k8 * 4 + 2) * 32 + tl] + sg[(k8 * 4 + 3) * 32 + tl];
        sg[1024 + k8 * 32 + tl] = sv;
    }
    __syncthreads();
    if (tid < 32) {
        float sv = 0.f;
#pragma unroll
        for (int w = 0; w < 8; w++) sv += sg[1024 + w * 32 + tid];
        float mb = sv;
#pragma unroll
        for (int o = 16; o > 0; o >>= 1) mb = fmaxf(mb, __shfl_xor(mb, o));
        float e = expf(sv - mb);
        float db = e;
#pragma unroll
        for (int o = 16; o > 0; o >>= 1) db += __shfl_xor(db, o);
        wl[tid] = e;
        if (tid == 0) {
            cstore(&pm[(na * 16 + tiq) * 2], mb);
            cstore(&pm[(na * 16 + tiq) * 2 + 1], db);
        }
    }
    __syncthreads();
    {
        int hp = (tid & 255) * 2, tis = (tid >> 8) * 8;
        int gb2 = hp >> 3, wrd = hp & 7;
        float a0 = 0.f, a1 = 0.f;
#pragma unroll
        for (int q = 0; q < 8; q++) {
            int tl = tis + q;
            unsigned u = *(const unsigned*)(enct + tl * 512 +
                                            ((gb2 ^ (tl & 7)) * 8) + wrd);
            float w = wl[tl];
            a0 = fmaf(w, bf2f(u & 0xffffu), a0);
            a1 = fmaf(w, bf2f(u >> 16), a1);
        }
        sg[1024 + (tid >> 8) * 512 + hp] = a0;
        sg[1024 + (tid >> 8) * 512 + hp + 1] = a1;
    }
    __syncthreads();
    if (tid < 512) {
        float v = sg[1024 + tid] + sg[1536 + tid] + sg[2048 + tid] + sg[2560 + tid];
        cstore(&pvec[((long)na * 16 + tiq) * 512 + tid], v);
    }
}

// one-time: enc 32-ti tile -> LDS (bf16, granule-swizzled)
__device__ __forceinline__ void load_tile(unsigned short* dst,
                                          const float* __restrict__ enc,
                                          int na, int tiq) {
    int tid = threadIdx.x;
    int tl = tid >> 5, gb = (tid & 31) * 2;
    const float* ebase = enc + ((long)na * TI + tiq * 32 + tl) * HH;
#pragma unroll
    for (int q = 0; q < 2; q++) {
        int gg = gb + q;
        const float* ep = ebase + gg * 8;
        float4 lo = *(const float4*)ep;
        float4 hi = *(const float4*)(ep + 4);
        uvec4 pk;
        pk.x = f2bf(lo.x) | (f2bf(lo.y) << 16);
        pk.y = f2bf(lo.z) | (f2bf(lo.w) << 16);
        pk.z = f2bf(hi.x) | (f2bf(hi.y) << 16);
        pk.w = f2bf(hi.z) | (f2bf(hi.w) << 16);
        *(uvec4*)(dst + tl * 512 + (gg ^ (tl & 7)) * 8) = pk;
    }
}

// final-step attention combine into mlpin[TT-1] (32 h per block per row)
__device__ __forceinline__ void epilogue_row(
    int na, int tiq, int hoff, const float* __restrict__ pvec,
    const float* __restrict__ pm, float* __restrict__ mlpin) {
    int h = tiq * 32 + hoff;
    float M = -1e30f, mm[16], dd[16];
#pragma unroll
    for (int bb = 0; bb < 16; bb++) {
        mm[bb] = cload1(&pm[(na * 16 + bb) * 2]);
        dd[bb] = cload1(&pm[(na * 16 + bb) * 2 + 1]);
        M = fmaxf(M, mm[bb]);
    }
    float den = 0.f, al[16];
#pragma unroll
    for (int bb = 0; bb < 16; bb++) { al[bb] = expf(mm[bb] - M); den += al[bb] * dd[bb]; }
    float inv = 1.f / den;
    float v = 0.f;
#pragma unroll
    for (int bb = 0; bb < 16; bb++)
        v += (al[bb] * inv) * cload1(&pvec[((long)na * 16 + bb) * 512 + h]);
    mlpin[((long)(TT - 1) * NB + na) * 1024 + 512 + h] = v;
}

// ---------------------------------------------------------------------------
// Persistent decode: 256 blocks x 1024 thr; each block serves slice s of TWO
// groups (A, B) of 2 batch rows each, alternating phases to hide barrier
// latency under the other group's compute. 16 groups x 32 slices.
// ---------------------------------------------------------------------------
__global__ __launch_bounds__(1024, 4) void decode_loop(
    const unsigned* __restrict__ Wtb0, const unsigned* __restrict__ Wtb1,
    const unsigned* __restrict__ Wtb2, const float* __restrict__ emb,
    const int* __restrict__ tokens, const float* __restrict__ enc,
    const float* __restrict__ b_ih0, const float* __restrict__ b_hh0,
    const float* __restrict__ b_ih_r, const float* __restrict__ b_hh_r,
    float* __restrict__ hbuf, float* __restrict__ pvec, float* __restrict__ pm,
    float* __restrict__ mlpin, int* flags) {
    __shared__ float2 xs2[1536];             // 12KB x-stage (shared A/B serially)
    __shared__ float sg[4096];               // 16KB scratch
    __shared__ float sg2[512];               // 2KB
    __shared__ float wl[32];
    __shared__ unsigned short enctA[16384];  // 32KB
    __shared__ unsigned short enctB[16384];  // 32KB

    int tid = threadIdx.x, b = blockIdx.x;
    int gp = b >> 5, s = b & 31;
    int gA = gp * 2, gB = gp * 2 + 1;
    int n0A = gp * 4, n0B = gp * 4 + 2;
    int epA = 0, epB = 0;
    int tiq = s & 15;
    int naA = n0A + (s >> 4), naB = n0B + (s >> 4);
    float cA0 = 0.f, cA1 = 0.f, cA2 = 0.f;
    float cB0 = 0.f, cB1 = 0.f, cB2 = 0.f;

    load_tile(enctA, enc, naA, tiq);
    load_tile(enctB, enc, naB, tiq);
    __syncthreads();

    for (int t = 0; t < TT; t++) {
        int rp = t & 1;
        float* hOld = hbuf + rp * 3 * NB * HH;
        float* hNew = hbuf + (rp ^ 1) * 3 * NB * HH;
        float* h0r = hOld;
        float* h1r = hOld + NB * HH;
        float* h2r = hOld + 2 * NB * HH;
        float* h0w = hNew;
        float* h1w = hNew + NB * HH;
        float* h2w = hNew + 2 * NB * HH;

        // P1
        if (t) gwait(flags, gA, epA);
        phase1(Wtb0, b_ih0, b_hh0, emb, tokens, t, h0r, h0w, cA0,
               pvec, pm, mlpin, xs2, sg, sg2, s, n0A);
        garrive(flags, gA, s, epA);
        if (t) gwait(flags, gB, epB);
        phase1(Wtb0, b_ih0, b_hh0, emb, tokens, t, h0r, h0w, cB0,
               pvec, pm, mlpin, xs2, sg, sg2, s, n0B);
        garrive(flags, gB, s, epB);

        // P2
        gwait(flags, gA, epA);
        phase23(Wtb1, b_ih_r, b_hh_r, h0w, h1r, h1w, cA1, nullptr,
                xs2, sg, sg2, s, n0A);
        garrive(flags, gA, s, epA);
        gwait(flags, gB, epB);
        phase23(Wtb1, b_ih_r, b_hh_r, h0w, h1r, h1w, cB1, nullptr,
                xs2, sg, sg2, s, n0B);
        garrive(flags, gB, s, epB);

        // P3
        gwait(flags, gA, epA);
        phase23(Wtb2, b_ih_r + G4, b_hh_r + G4, h1w, h2r, h2w, cA2,
                mlpin + (long)t * NB * 1024, xs2, sg, sg2, s, n0A);
        garrive(flags, gA, s, epA);
        gwait(flags, gB, epB);
        phase23(Wtb2, b_ih_r + G4, b_hh_r + G4, h1w, h2r, h2w, cB2,
                mlpin + (long)t * NB * 1024, xs2, sg, sg2, s, n0B);
        garrive(flags, gB, s, epB);

        // P45
        gwait(flags, gA, epA);
        phase45(enctA, h2w, naA, tiq, pvec, pm, sg, sg2, wl);
        garrive(flags, gA, s, epA);
        gwait(flags, gB, epB);
        phase45(enctB, h2w, naB, tiq, pvec, pm, sg, sg2, wl);
        garrive(flags, gB, s, epB);
    }

    // epilogue: final-step attention -> mlpin[TT-1] att-half
    gwait(flags, gA, epA);
    gwait(flags, gB, epB);
    if (tid < 32) epilogue_row(naA, tiq, tid, pvec, pm, mlpin);
    else if (tid < 64) epilogue_row(naB, tiq, tid - 32, pvec, pm, mlpin);
}

// ---------------------------------------------------------------------------
// LSTM weight transpose -> bf16 quad-packed, slice-permuted columns (as r11+).
// ---------------------------------------------------------------------------
__global__ void transpose_lstm_q(const float* __restrict__ Wih, int KA,
                                 const float* __restrict__ Whh,
                                 unsigned* __restrict__ Wtb) {
    int K = KA + 512;
    long total = (long)(K / 4) * 4096;
    for (long idx = (long)blockIdx.x * 256 + threadIdx.x; idx < total;
         idx += (long)gridDim.x * 256) {
        int c2 = (int)(idx % 4096);
        int kq = (int)(idx / 4096);
        int c = c2 >> 1, half = c2 & 1;
        int sI = c >> 6, r = c & 63, gg = r >> 4, ml = r & 15;
        int j = gg * 512 + sI * 16 + ml;
        int k0 = kq * 4 + half * 2, k1 = k0 + 1;
        float w0 = (k0 < KA) ? Wih[(long)j * KA + k0] : Whh[(long)j * 512 + (k0 - KA)];
        float w1 = (k1 < KA) ? Wih[(long)j * KA + k1] : Whh[(long)j * 512 + (k1 - KA)];
        Wtb[idx] = f2bf(w0) | (f2bf(w1) << 16);
    }
}

// W2 -> plain bf16 [10240][512]: Wb[j*256+kk] = pair(W2[j][2kk], W2[j][2kk+1])
__global__ void transpose_w2_bf(const float* __restrict__ W2,
                                unsigned* __restrict__ Wb) {
    long total = (long)10240 * 256;
    for (long idx = (long)blockIdx.x * 256 + threadIdx.x; idx < total;
         idx += (long)gridDim.x * 256) {
        int kk = (int)(idx & 255);
        int j = (int)(idx >> 8);
        float lo = 0.f, hi = 0.f;
        if (j < VV) {
            lo = W2[(long)j * 512 + 2 * kk];
            hi = W2[(long)j * 512 + 2 * kk + 1];
        }
        Wb[idx] = packbf2(lo, hi);
    }
}

// fp32 transpose (MLP1): Wt[k][j] = A[j][k]
__global__ void transpose_cat(const float* __restrict__ A, int KA,
                              int J, int Jp, float* __restrict__ Wt) {
    long total = (long)KA * Jp;
    for (long idx = (long)blockIdx.x * 256 + threadIdx.x; idx < total;
         idx += (long)gridDim.x * 256) {
        int j = (int)(idx % Jp);
        int k = (int)(idx / Jp);
        Wt[idx] = (j < J) ? A[(long)j * KA + k] : 0.f;
    }
}

// ---------------------------------------------------------------------------
// MLP1: 8 rows/block, thread owns cols (2jp, 2jp+1); bf16-pair output.
// ---------------------------------------------------------------------------
__global__ void gemm_mlp1(const float* __restrict__ Wt,
                          const float* __restrict__ X,
                          const float* __restrict__ bias,
                          unsigned* __restrict__ outb) {
    __shared__ float xs[64 * 12];
    int m0 = blockIdx.x * 8;
    int lane = threadIdx.x & 63;
    int wv = threadIdx.x >> 6;
    int jp = wv * 64 + lane;
    float acc0[8], acc1[8];
#pragma unroll
    for (int q = 0; q < 8; q++) { acc0[q] = 0.f; acc1[q] = 0.f; }
    for (int kc = 0; kc < 1024; kc += 64) {
        __syncthreads();
        for (int idx = threadIdx.x; idx < 512; idx += 256) {
            int k = idx >> 3, n = idx & 7;
            xs[k * 12 + n] = X[(long)(m0 + n) * 1024 + kc + k];
        }
        __syncthreads();
        const float2* wpp = (const float2*)(Wt + (long)kc * 512) + jp;
#pragma unroll 4
        for (int k = 0; k < 64; k++) {
            float2 w = wpp[(long)k * 256];
            const float4* xv = (const float4*)(xs + k * 12);
            float4 x0 = xv[0], x1 = xv[1];
            acc0[0] += w.x * x0.x; acc0[1] += w.x * x0.y;
            acc0[2] += w.x * x0.z; acc0[3] += w.x * x0.w;
            acc0[4] += w.x * x1.x; acc0[5] += w.x * x1.y;
            acc0[6] += w.x * x1.z; acc0[7] += w.x * x1.w;
            acc1[0] += w.y * x0.x; acc1[1] += w.y * x0.y;
            acc1[2] += w.y * x0.z; acc1[3] += w.y * x0.w;
            acc1[4] += w.y * x1.x; acc1[5] += w.y * x1.y;
            acc1[6] += w.y * x1.z; acc1[7] += w.y * x1.w;
        }
    }
    float b0 = bias[2 * jp], b1 = bias[2 * jp + 1];
#pragma unroll
    for (int n = 0; n < 8; n++) {
        float v0 = tanhf(acc0[n] + b0);
        float v1 = tanhf(acc1[n] + b1);
        outb[(long)(m0 + n) * 256 + jp] = packbf2(v0, v1);
    }
}

// ---------------------------------------------------------------------------
// MLP2 via MFMA 16x16x32 bf16 (verified r15). Block = 32 rows x 256 cols.
// ---------------------------------------------------------------------------
__device__ __forceinline__ bf16x8 ldfrag(const unsigned short* p) {
    bf16x4 lo = *(const bf16x4*)p;
    bf16x4 hi = *(const bf16x4*)(p + 16);
    bf16x8 r;
    r[0] = lo[0]; r[1] = lo[1]; r[2] = lo[2]; r[3] = lo[3];
    r[4] = hi[0]; r[5] = hi[1]; r[6] = hi[2]; r[7] = hi[3];
    return r;
}

__global__ __launch_bounds__(256) void gemm_mlp2_mfma(
    const unsigned short* __restrict__ Wb2,   // [10240][512] bf16
    const unsigned short* __restrict__ Yb,    // [2080][512] bf16
    const float* __restrict__ bias,
    float* __restrict__ out) {
    int t = blockIdx.y;
    int m0 = t * 32;
    int l = threadIdx.x & 63, w = threadIdx.x >> 6;
    int colbase = blockIdx.x * 256 + w * 64;
    int r16 = l & 15, kq = l >> 4;
    f32x4 acc[2][4];
#pragma unroll
    for (int i = 0; i < 2; i++)
#pragma unroll
        for (int j = 0; j < 4; j++) acc[i][j] = (f32x4){0.f, 0.f, 0.f, 0.f};

    const unsigned short* a0p = Yb + (long)(m0 + r16) * 512 + kq * 4;
    const unsigned short* a1p = a0p + 16 * 512;
#pragma unroll 2
    for (int ks = 0; ks < 16; ks++) {
        int kb = ks * 32;
        bf16x8 a0 = ldfrag(a0p + kb);
        bf16x8 a1 = ldfrag(a1p + kb);
#pragma unroll
        for (int ct = 0; ct < 4; ct++) {
            const unsigned short* bp =
                Wb2 + (long)(colbase + ct * 16 + r16) * 512 + kb + kq * 4;
            bf16x8 bf = ldfrag(bp);
            acc[0][ct] = __builtin_amdgcn_mfma_f32_16x16x32_bf16(a0, bf, acc[0][ct], 0, 0, 0);
            acc[1][ct] = __builtin_amdgcn_mfma_f32_16x16x32_bf16(a1, bf, acc[1][ct], 0, 0, 0);
        }
    }
#pragma unroll
    for (int mi = 0; mi < 2; mi++)
#pragma unroll
        for (int ct = 0; ct < 4; ct++) {
            int col = colbase + ct * 16 + r16;
            if (col < VV) {
                float bv = bias[col];
#pragma unroll
                for (int r = 0; r < 4; r++) {
                    int nn = mi * 16 + kq * 4 + r;
                    out[((long)nn * TT + t) * VV + col] = acc[mi][ct][r] + bv;
                }
            }
        }
}

__global__ void loss_rows(const float* __restrict__ out, const int* __restrict__ tokens,
                          float* __restrict__ nll) {
    __shared__ float red[256];
    int row = blockIdx.x;
    int n = row / TT, t = row % TT;
    const float* y = out + (long)row * VV;
    int tid = threadIdx.x;
    float m = -1e30f;
    for (int v = tid; v < VV; v += 256) m = fmaxf(m, y[v]);
    red[tid] = m;
    __syncthreads();
    for (int s = 128; s > 0; s >>= 1) {
        if (tid < s) red[tid] = fmaxf(red[tid], red[tid + s]);
        __syncthreads();
    }
    m = red[0];
    __syncthreads();
    float sum = 0.f;
    for (int v = tid; v < VV; v += 256) sum += expf(y[v] - m);
    red[tid] = sum;
    __syncthreads();
    for (int s = 128; s > 0; s >>= 1) {
        if (tid < s) red[tid] += red[tid + s];
        __syncthreads();
    }
    if (tid == 0) {
        int target = (t < TO) ? tokens[n * TO + t] : EOS_ID;
        nll[row] = m + logf(red[0]) - y[target];
    }
}

__global__ void loss_final(const float* __restrict__ nll, float* __restrict__ out_loss) {
    __shared__ float red[256];
    int tid = threadIdx.x;
    float s = 0.f;
    for (int i = tid; i < NB * TT; i += 256) s += nll[i];
    red[tid] = s;
    __syncthreads();
    for (int k = 128; k > 0; k >>= 1) {
        if (tid < k) red[tid] += red[tid + k];
        __syncthreads();
    }
    if (tid == 0) *out_loss = red[0] / (float)(NB * TT);
}

extern "C" void kernel_launch(void* const* d_in, const int* in_sizes, int n_in,
                              void* d_out, int out_size, void* d_ws, size_t ws_size,
                              hipStream_t stream) {
    const int* padded   = (const int*)d_in[0];
    const float* enc    = (const float*)d_in[1];
    const float* emb    = (const float*)d_in[2];
    const float* W_ih0  = (const float*)d_in[3];
    const float* W_hh0  = (const float*)d_in[4];
    const float* b_ih0  = (const float*)d_in[5];
    const float* b_hh0  = (const float*)d_in[6];
    const float* W_ih_r = (const float*)d_in[7];
    const float* W_hh_r = (const float*)d_in[8];
    const float* b_ih_r = (const float*)d_in[9];
    const float* b_hh_r = (const float*)d_in[10];
    const float* W1     = (const float*)d_in[11];
    const float* b1     = (const float*)d_in[12];
    const float* W2     = (const float*)d_in[13];
    const float* b2     = (const float*)d_in[14];
    float* out = (float*)d_out;
    float* ws  = (float*)d_ws;

    // workspace (dwords)
    unsigned* Wtb0 = (unsigned*)ws;              // [384][4096]
    unsigned* Wtb1 = Wtb0 + 384 * 4096;          // [256][4096]
    unsigned* Wtb2 = Wtb1 + 256 * 4096;          // [256][4096]
    unsigned* Wb2u = Wtb2 + 256 * 4096;          // [10240][256] (bf16 pairs)
    float* Wm1  = (float*)(Wb2u + 10240 * 256);  // [1024][512]
    float* hbuf = Wm1 + 1024 * 512;              // [2][3][32][512]
    float* mlpin= hbuf + 2 * 3 * NB * HH;        // [65][32][1024]
    unsigned* y1b = (unsigned*)(mlpin + (long)TT * NB * 1024);  // [2080][256]
    float* pvec = (float*)(y1b + (long)TT * NB * 256);          // [32][16][512]
    float* pm   = pvec + 32 * 16 * 512;          // [32][16][2]
    float* nll  = pm + 1024;                     // [2080]
    int*   flags= (int*)(nll + 2080);            // [16][32][16]

    hipMemsetAsync(hbuf, 0, (size_t)(2 * 3 * NB * HH) * sizeof(float), stream);
    hipMemsetAsync(flags, 0, 16 * 32 * 16 * sizeof(int), stream);

    transpose_cat<<<1024, 256, 0, stream>>>(W1, 1024, 512, 512, Wm1);
    transpose_lstm_q<<<2048, 256, 0, stream>>>(W_ih0, 1024, W_hh0, Wtb0);
    transpose_lstm_q<<<2048, 256, 0, stream>>>(W_ih_r, 512, W_hh_r, Wtb1);
    transpose_lstm_q<<<2048, 256, 0, stream>>>(W_ih_r + 2048 * 512, 512,
                                               W_hh_r + 2048 * 512, Wtb2);
    transpose_w2_bf<<<2048, 256, 0, stream>>>(W2, Wb2u);

    decode_loop<<<NBLK, 1024, 0, stream>>>(Wtb0, Wtb1, Wtb2, emb, padded, enc,
                                           b_ih0, b_hh0, b_ih_r, b_hh_r,
                                           hbuf, pvec, pm, mlpin, flags);

    gemm_mlp1<<<260, 256, 0, stream>>>(Wm1, mlpin, b1, y1b);
    gemm_mlp2_mfma<<<dim3(40, TT), 256, 0, stream>>>(
        (const unsigned short*)Wb2u, (const unsigned short*)y1b, b2, out);
    loss_rows<<<NB * TT, 256, 0, stream>>>(out, padded, nll);
    loss_final<<<1, 256, 0, stream>>>(nll, out + (long)NB * TT * VV);
}

// Round 17
// 2193.607 us; speedup vs baseline: 2.1422x; 2.1422x over previous
//
#include <hip/hip_runtime.h>
#include <hip/hip_bf16.h>
#include <hip/hip_fp16.h>

// Problem constants
#define NB 32
#define TO 64
#define TT 65
#define TI 512
#define VV 10000
#define HH 512
#define G4 2048
#define SOS_ID 1
#define EOS_ID 2
#define NBLK 256

typedef unsigned uvec4 __attribute__((ext_vector_type(4)));
typedef unsigned uvec2 __attribute__((ext_vector_type(2)));
typedef short bf16x4 __attribute__((ext_vector_type(4)));
typedef short bf16x8 __attribute__((ext_vector_type(8)));
typedef float f32x4 __attribute__((ext_vector_type(4)));

__device__ __forceinline__ float cload1(const float* p) {
    unsigned v = __hip_atomic_load((const unsigned*)p,
                                   __ATOMIC_RELAXED, __HIP_MEMORY_SCOPE_AGENT);
    return __uint_as_float(v);
}
__device__ __forceinline__ float2 cload2(const float* p) {
    unsigned long long v = __hip_atomic_load((const unsigned long long*)p,
                                             __ATOMIC_RELAXED, __HIP_MEMORY_SCOPE_AGENT);
    float2 r;
    r.x = __uint_as_float((unsigned)(v & 0xffffffffull));
    r.y = __uint_as_float((unsigned)(v >> 32));
    return r;
}
__device__ __forceinline__ void cstore(float* p, float v) {
    __hip_atomic_store((unsigned*)p, __float_as_uint(v),
                       __ATOMIC_RELAXED, __HIP_MEMORY_SCOPE_AGENT);
}

// Combined flag-array group barrier (round-11/13/14 proven).
__device__ __forceinline__ void gbar(int* flags, int g, int s, int& epoch) {
    asm volatile("s_waitcnt vmcnt(0) lgkmcnt(0)" ::: "memory");
    __syncthreads();
    epoch++;
    int tid = threadIdx.x;
    if (tid == 0)
        __hip_atomic_store(&flags[(g * 32 + s) * 16], epoch,
                           __ATOMIC_RELAXED, __HIP_MEMORY_SCOPE_AGENT);
    if (tid < 32) {
        for (;;) {
            int v = __hip_atomic_load(&flags[(g * 32 + tid) * 16],
                                      __ATOMIC_RELAXED, __HIP_MEMORY_SCOPE_AGENT);
            unsigned long long b = __ballot(v >= epoch);
            if ((b & 0xffffffffull) == 0xffffffffull) break;
            __builtin_amdgcn_s_sleep(1);
        }
    }
    __syncthreads();
}

__device__ __forceinline__ float bf2f(unsigned u16) {
    return __uint_as_float(u16 << 16);
}
__device__ __forceinline__ unsigned f2bf(float f) {
    unsigned u = __float_as_uint(f);
    return (u + 0x7fffu + ((u >> 16) & 1u)) >> 16;
}
__device__ __forceinline__ unsigned packbf2(float a, float b) {
    return f2bf(a) | (f2bf(b) << 16);
}

// ---------------------------------------------------------------------------
// Fused LSTM phase (round-13/14): 16-wave k-split, bf16 quad-packed weights,
// two-level reduce, gating on tid<64 while tid 512..767 prestage next input.
// ---------------------------------------------------------------------------
template <int KQ4>  // quads per wave: 24 (L0) or 16 (L1,L2)
__device__ __forceinline__ void lstm_phase(
    const unsigned* __restrict__ Wtb, const float* __restrict__ bi,
    const float* __restrict__ bh, float* __restrict__ hout,
    float& creg, float* __restrict__ mlprow,
    float4* xs4, float* sg, float* sg2, int s, int n0,
    const float* __restrict__ pre) {
    int tid = threadIdx.x;
    int lane = tid & 63, wv = tid >> 6;
    const uvec2* wp = (const uvec2*)Wtb + (long)(wv * KQ4) * 2048 + (s * 64 + lane);
    const float4* xp = (const float4*)xs4 + wv * KQ4 * 4;
    float a0 = 0.f, a1 = 0.f, a2 = 0.f, a3 = 0.f;
#pragma unroll 4
    for (int kq = 0; kq < KQ4; kq++) {
        uvec2 u = wp[(long)kq * 2048];
        float w0 = bf2f(u.x & 0xffffu), w1 = bf2f(u.x >> 16);
        float w2 = bf2f(u.y & 0xffffu), w3 = bf2f(u.y >> 16);
        float4 x0 = xp[4 * kq], x1 = xp[4 * kq + 1];
        float4 x2 = xp[4 * kq + 2], x3 = xp[4 * kq + 3];
        a0 = fmaf(w0, x0.x, a0); a1 = fmaf(w0, x0.y, a1);
        a2 = fmaf(w0, x0.z, a2); a3 = fmaf(w0, x0.w, a3);
        a0 = fmaf(w1, x1.x, a0); a1 = fmaf(w1, x1.y, a1);
        a2 = fmaf(w1, x1.z, a2); a3 = fmaf(w1, x1.w, a3);
        a0 = fmaf(w2, x2.x, a0); a1 = fmaf(w2, x2.y, a1);
        a2 = fmaf(w2, x2.z, a2); a3 = fmaf(w2, x2.w, a3);
        a0 = fmaf(w3, x3.x, a0); a1 = fmaf(w3, x3.y, a1);
        a2 = fmaf(w3, x3.z, a2); a3 = fmaf(w3, x3.w, a3);
    }
    float4 r4; r4.x = a0; r4.y = a1; r4.z = a2; r4.w = a3;
    ((float4*)sg)[wv * 64 + lane] = r4;
    __syncthreads();
    {   // first-level reduce: thread (c, n, w4) sums 4 wave-partials
        int c = tid >> 4, n = (tid >> 2) & 3, w4 = tid & 3;
        float sum = sg[((w4 * 4 + 0) * 64 + c) * 4 + n]
                  + sg[((w4 * 4 + 1) * 64 + c) * 4 + n]
                  + sg[((w4 * 4 + 2) * 64 + c) * 4 + n]
                  + sg[((w4 * 4 + 3) * 64 + c) * 4 + n];
        sg2[tid] = sum;
    }
    __syncthreads();
    if (tid < 64) {
        int gn = tid >> 4, gml = tid & 15, gm = s * 16 + gml;
        float ga[4];
#pragma unroll
        for (int q = 0; q < 4; q++) {
            int c = q * 16 + gml;
            const float* p = sg2 + c * 16 + gn * 4;
            ga[q] = p[0] + p[1] + p[2] + p[3];
        }
        float gi = ga[0] + bi[gm] + bh[gm];
        float gf = ga[1] + bi[512 + gm] + bh[512 + gm];
        float gg = ga[2] + bi[1024 + gm] + bh[1024 + gm];
        float go = ga[3] + bi[1536 + gm] + bh[1536 + gm];
        float si = 1.f / (1.f + expf(-gi));
        float sf = 1.f / (1.f + expf(-gf));
        float so = 1.f / (1.f + expf(-go));
        float c2 = sf * creg + si * tanhf(gg);
        creg = c2;
        float hv = so * tanhf(c2);
        cstore(&hout[(n0 + gn) * 512 + gm], hv);
        if (mlprow) mlprow[(long)(n0 + gn) * 1024 + gm] = hv;
    } else if (pre && tid >= 512 && tid < 768) {
        int k = 512 + (tid - 512) * 2;
        float2 va = cload2(pre + (n0 + 0) * 512 + (k - 512));
        float2 vb = cload2(pre + (n0 + 1) * 512 + (k - 512));
        float2 vc = cload2(pre + (n0 + 2) * 512 + (k - 512));
        float2 vd = cload2(pre + (n0 + 3) * 512 + (k - 512));
        float4 x0, x1;
        x0.x = va.x; x0.y = vb.x; x0.z = vc.x; x0.w = vd.x;
        x1.x = va.y; x1.y = vb.y; x1.z = vc.y; x1.w = vd.y;
        xs4[k] = x0; xs4[k + 1] = x1;
    }
}

// ---------------------------------------------------------------------------
// Persistent decode: 8 groups x 32 blocks x 1024 thr; 4 barriers/step.
// Attention = per-block tile partial softmax; combine in next P1.
// ---------------------------------------------------------------------------
__global__ __launch_bounds__(1024, 4) void decode_loop(
    const unsigned* __restrict__ Wtb0, const unsigned* __restrict__ Wtb1,
    const unsigned* __restrict__ Wtb2, const float* __restrict__ emb,
    const int* __restrict__ tokens, const float* __restrict__ enc,
    const float* __restrict__ b_ih0, const float* __restrict__ b_hh0,
    const float* __restrict__ b_ih_r, const float* __restrict__ b_hh_r,
    float* __restrict__ hbuf, float* __restrict__ pvec, float* __restrict__ pm,
    float* __restrict__ mlpin, int* flags) {
    __shared__ float4 xs4[1536];            // 24KB x-stage
    __shared__ float sg[4096];              // 16KB partials / scratch
    __shared__ float sg2[1024];             // 4KB reduce level-1 / h2 stage
    __shared__ float wl[64];                // tile-local exp weights
    __shared__ unsigned short enct[32768];  // 64KB swizzled enc tile

    int tid = threadIdx.x, b = blockIdx.x;
    int g = b >> 5, s = b & 31;
    int epoch = 0;
    int n0 = g * 4;
    int na = n0 + (s >> 3), tiq = s & 7;
    float c0r = 0.f, c1r = 0.f, c2r = 0.f;

    {   // one-time enc tile -> LDS (bf16, swizzled)
        int tl = tid >> 4;
        int gb = (tid & 15) * 4;
        const float* ebase = enc + ((long)na * TI + tiq * 64 + tl) * HH;
#pragma unroll
        for (int q = 0; q < 4; q++) {
            int gg = gb + q;
            const float* ep = ebase + gg * 8;
            float4 lo = *(const float4*)ep;
            float4 hi = *(const float4*)(ep + 4);
            uvec4 pk;
            pk.x = f2bf(lo.x) | (f2bf(lo.y) << 16);
            pk.y = f2bf(lo.z) | (f2bf(lo.w) << 16);
            pk.z = f2bf(hi.x) | (f2bf(hi.y) << 16);
            pk.w = f2bf(hi.z) | (f2bf(hi.w) << 16);
            *(uvec4*)(enct + tl * 512 + (gg ^ (tl & 7)) * 8) = pk;
        }
    }
    __syncthreads();

    for (int t = 0; t < TT; t++) {
        int rp = t & 1;
        float* hOld = hbuf + rp * 3 * NB * HH;
        float* hNew = hbuf + (rp ^ 1) * 3 * NB * HH;
        float* h0r = hOld;
        float* h1r = hOld + NB * HH;
        float* h2r = hOld + 2 * NB * HH;
        float* h0w = hNew;
        float* h1w = hNew + NB * HH;
        float* h2w = hNew + 2 * NB * HH;

        // ===== P1: L0 LSTM, x=[emb|att|h0r], K=1536 =====
        if (t == 0) {
            if (tid < 768) {
                int k = tid * 2;
                float2 va, vb, vc, vd;
                if (k < 512) {
                    va = *(const float2*)(emb + (long)SOS_ID * 512 + k);
                    vb = va; vc = va; vd = va;
                } else if (k < 1024) {
                    va.x = va.y = 0.f; vb = va; vc = va; vd = va;
                } else {
                    int kk = k - 1024;
                    va = cload2(h0r + (n0 + 0) * 512 + kk);
                    vb = cload2(h0r + (n0 + 1) * 512 + kk);
                    vc = cload2(h0r + (n0 + 2) * 512 + kk);
                    vd = cload2(h0r + (n0 + 3) * 512 + kk);
                }
                float4 x0, x1;
                x0.x = va.x; x0.y = vb.x; x0.z = vc.x; x0.w = vd.x;
                x1.x = va.y; x1.y = vb.y; x1.z = vc.y; x1.w = vd.y;
                xs4[k] = x0; xs4[k + 1] = x1;
            }
            __syncthreads();
        } else {
            // emb + h0r prestaged during P45(t-1). Combine attention partials.
            if (tid < 32) {
                int nn = tid >> 3, bb = tid & 7;
                sg[tid * 2] = cload1(&pm[((n0 + nn) * 8 + bb) * 2]);
                sg[tid * 2 + 1] = cload1(&pm[((n0 + nn) * 8 + bb) * 2 + 1]);
            }
            __syncthreads();
            {
                int nn = tid >> 8, hp = (tid & 255) * 2;
                float M = -1e30f;
#pragma unroll
                for (int bb = 0; bb < 8; bb++) M = fmaxf(M, sg[(nn * 8 + bb) * 2]);
                float al[8];
                float den = 0.f;
#pragma unroll
                for (int bb = 0; bb < 8; bb++) {
                    al[bb] = expf(sg[(nn * 8 + bb) * 2] - M);
                    den += al[bb] * sg[(nn * 8 + bb) * 2 + 1];
                }
                float inv = 1.f / den;
                float a0 = 0.f, a1 = 0.f;
#pragma unroll
                for (int bb = 0; bb < 8; bb++) {
                    float c = al[bb] * inv;
                    float2 v = cload2(&pvec[((long)(n0 + nn) * 8 + bb) * 512 + hp]);
                    a0 = fmaf(c, v.x, a0);
                    a1 = fmaf(c, v.y, a1);
                }
                sg[1024 + nn * 512 + hp] = a0;
                sg[1024 + nn * 512 + hp + 1] = a1;
            }
            __syncthreads();
            if (tid < 256) {
                int kk = tid * 2;
                float v0a = sg[1024 + 0 * 512 + kk], v0b = sg[1024 + 0 * 512 + kk + 1];
                float v1a = sg[1024 + 1 * 512 + kk], v1b = sg[1024 + 1 * 512 + kk + 1];
                float v2a = sg[1024 + 2 * 512 + kk], v2b = sg[1024 + 2 * 512 + kk + 1];
                float v3a = sg[1024 + 3 * 512 + kk], v3b = sg[1024 + 3 * 512 + kk + 1];
                if ((kk >> 4) == s) {   // exactly-one-block writer for mlpin att-half
                    float* mp = mlpin + ((long)(t - 1) * NB + n0) * 1024 + 512 + kk;
                    mp[0] = v0a; mp[1] = v0b;
                    mp[1024] = v1a; mp[1025] = v1b;
                    mp[2048] = v2a; mp[2049] = v2b;
                    mp[3072] = v3a; mp[3073] = v3b;
                }
                float4 x0, x1;
                x0.x = v0a; x0.y = v1a; x0.z = v2a; x0.w = v3a;
                x1.x = v0b; x1.y = v1b; x1.z = v2b; x1.w = v3b;
                xs4[512 + kk] = x0; xs4[512 + kk + 1] = x1;
            }
            __syncthreads();
        }
        lstm_phase<24>(Wtb0, b_ih0, b_hh0, h0w, c0r, nullptr,
                       xs4, sg, sg2, s, n0, h1r);   // prestage h1r
        gbar(flags, g, s, epoch);

        // ===== P2: L1 LSTM, x=[h0w|h1r(prestaged)] =====
        if (tid < 256) {
            int k = tid * 2;
            float2 va = cload2(h0w + (n0 + 0) * 512 + k);
            float2 vb = cload2(h0w + (n0 + 1) * 512 + k);
            float2 vc = cload2(h0w + (n0 + 2) * 512 + k);
            float2 vd = cload2(h0w + (n0 + 3) * 512 + k);
            float4 x0, x1;
            x0.x = va.x; x0.y = vb.x; x0.z = vc.x; x0.w = vd.x;
            x1.x = va.y; x1.y = vb.y; x1.z = vc.y; x1.w = vd.y;
            xs4[k] = x0; xs4[k + 1] = x1;
        }
        __syncthreads();
        lstm_phase<16>(Wtb1, b_ih_r, b_hh_r, h1w, c1r, nullptr,
                       xs4, sg, sg2, s, n0, h2r);   // prestage h2r
        gbar(flags, g, s, epoch);

        // ===== P3: L2 LSTM, x=[h1w|h2r(prestaged)] =====
        if (tid < 256) {
            int k = tid * 2;
            float2 va = cload2(h1w + (n0 + 0) * 512 + k);
            float2 vb = cload2(h1w + (n0 + 1) * 512 + k);
            float2 vc = cload2(h1w + (n0 + 2) * 512 + k);
            float2 vd = cload2(h1w + (n0 + 3) * 512 + k);
            float4 x0, x1;
            x0.x = va.x; x0.y = vb.x; x0.z = vc.x; x0.w = vd.x;
            x1.x = va.y; x1.y = vb.y; x1.z = vc.y; x1.w = vd.y;
            xs4[k] = x0; xs4[k + 1] = x1;
        }
        __syncthreads();
        lstm_phase<16>(Wtb2, b_ih_r + G4, b_hh_r + G4, h2w, c2r,
                       mlpin + (long)t * NB * 1024,
                       xs4, sg, sg2, s, n0, nullptr);
        gbar(flags, g, s, epoch);

        // ===== P45: scores + TILE-LOCAL softmax + partial apply =====
        if (tid < 512) sg2[tid] = cload1(h2w + na * 512 + tid);
        __syncthreads();
        {
            int tl = tid & 63, kh = tid >> 6;
            float acc = 0.f;
#pragma unroll
            for (int q = 0; q < 4; q++) {
                int gg = kh * 4 + q;
                uvec4 e = *(const uvec4*)(enct + tl * 512 + ((gg ^ (tl & 7)) * 8));
                const float* hp = sg2 + gg * 8;
                acc += bf2f(e.x & 0xffffu) * hp[0] + bf2f(e.x >> 16) * hp[1]
                     + bf2f(e.y & 0xffffu) * hp[2] + bf2f(e.y >> 16) * hp[3]
                     + bf2f(e.z & 0xffffu) * hp[4] + bf2f(e.z >> 16) * hp[5]
                     + bf2f(e.w & 0xffffu) * hp[6] + bf2f(e.w >> 16) * hp[7];
            }
            sg[tid] = acc;
        }
        __syncthreads();
        if (tid < 64) {
            float sv = 0.f;
#pragma unroll
            for (int w = 0; w < 16; w++) sv += sg[tid + 64 * w];
            float mb = sv;
#pragma unroll
            for (int o = 32; o > 0; o >>= 1) mb = fmaxf(mb, __shfl_xor(mb, o));
            float e = expf(sv - mb);
            float db = e;
#pragma unroll
            for (int o = 32; o > 0; o >>= 1) db += __shfl_xor(db, o);
            wl[tid] = e;
            if (tid == 0) {
                cstore(&pm[(na * 8 + tiq) * 2], mb);
                cstore(&pm[(na * 8 + tiq) * 2 + 1], db);
            }
        }
        __syncthreads();
        {
            int hp = (tid & 255) * 2, tis = (tid >> 8) * 16;
            int gb2 = hp >> 3, wrd = hp & 7;
            float a0 = 0.f, a1 = 0.f;
#pragma unroll 8
            for (int q = 0; q < 16; q++) {
                int tl = tis + q;
                unsigned u = *(const unsigned*)(enct + tl * 512 +
                                                ((gb2 ^ (tl & 7)) * 8) + wrd);
                float w = wl[tl];
                a0 = fmaf(w, bf2f(u & 0xffffu), a0);
                a1 = fmaf(w, bf2f(u >> 16), a1);
            }
            float* prt = sg + 1024;
            prt[(tid >> 8) * 512 + hp] = a0;
            prt[(tid >> 8) * 512 + hp + 1] = a1;
            __syncthreads();
            if (tid < 512) {
                int h = tid;
                float v = prt[h] + prt[512 + h] + prt[1024 + h] + prt[1536 + h];
                cstore(&pvec[((long)na * 8 + tiq) * 512 + h], v);
            }
            // prestage emb + h0(t+1)=h0w for next P1 (xs4 unused in P45)
            if (t + 1 < TT) {
                if (tid < 512) {
                    int k = tid;
                    int r0 = tokens[(n0 + 0) * TO + t];
                    int r1 = tokens[(n0 + 1) * TO + t];
                    int r2 = tokens[(n0 + 2) * TO + t];
                    int r3 = tokens[(n0 + 3) * TO + t];
                    float4 v;
                    v.x = emb[(long)r0 * 512 + k];
                    v.y = emb[(long)r1 * 512 + k];
                    v.z = emb[(long)r2 * 512 + k];
                    v.w = emb[(long)r3 * 512 + k];
                    xs4[k] = v;
                } else {
                    int k = tid - 512;
                    float4 v;
                    v.x = cload1(h0w + (n0 + 0) * 512 + k);
                    v.y = cload1(h0w + (n0 + 1) * 512 + k);
                    v.z = cload1(h0w + (n0 + 2) * 512 + k);
                    v.w = cload1(h0w + (n0 + 3) * 512 + k);
                    xs4[1024 + k] = v;
                }
            }
        }
        gbar(flags, g, s, epoch);
    }

    // epilogue: combine final step's attention into mlpin[TT-1] att-half
    if (tid < 64) {
        int h = tiq * 64 + tid;
        float mm[8], dd[8], al[8];
        float M = -1e30f;
#pragma unroll
        for (int bb = 0; bb < 8; bb++) {
            mm[bb] = cload1(&pm[(na * 8 + bb) * 2]);
            dd[bb] = cload1(&pm[(na * 8 + bb) * 2 + 1]);
            M = fmaxf(M, mm[bb]);
        }
        float den = 0.f;
#pragma unroll
        for (int bb = 0; bb < 8; bb++) { al[bb] = expf(mm[bb] - M); den += al[bb] * dd[bb]; }
        float inv = 1.f / den;
        float v = 0.f;
#pragma unroll
        for (int bb = 0; bb < 8; bb++)
            v += (al[bb] * inv) * cload1(&pvec[((long)na * 8 + bb) * 512 + h]);
        mlpin[((long)(TT - 1) * NB + na) * 1024 + 512 + h] = v;
    }
}

// ---------------------------------------------------------------------------
// LSTM weight transpose -> bf16 quad-packed, slice-permuted columns.
// ---------------------------------------------------------------------------
__global__ void transpose_lstm_q(const float* __restrict__ Wih, int KA,
                                 const float* __restrict__ Whh,
                                 unsigned* __restrict__ Wtb) {
    int K = KA + 512;
    long total = (long)(K / 4) * 4096;
    for (long idx = (long)blockIdx.x * 256 + threadIdx.x; idx < total;
         idx += (long)gridDim.x * 256) {
        int c2 = (int)(idx % 4096);
        int kq = (int)(idx / 4096);
        int c = c2 >> 1, half = c2 & 1;
        int sI = c >> 6, r = c & 63, gg = r >> 4, ml = r & 15;
        int j = gg * 512 + sI * 16 + ml;
        int k0 = kq * 4 + half * 2, k1 = k0 + 1;
        float w0 = (k0 < KA) ? Wih[(long)j * KA + k0] : Whh[(long)j * 512 + (k0 - KA)];
        float w1 = (k1 < KA) ? Wih[(long)j * KA + k1] : Whh[(long)j * 512 + (k1 - KA)];
        Wtb[idx] = f2bf(w0) | (f2bf(w1) << 16);
    }
}

// W2 -> plain bf16 [10240][512] (dword = k-pair): Wb[j*256+kk]
__global__ void transpose_w2_bf(const float* __restrict__ W2,
                                unsigned* __restrict__ Wb) {
    long total = (long)10240 * 256;
    for (long idx = (long)blockIdx.x * 256 + threadIdx.x; idx < total;
         idx += (long)gridDim.x * 256) {
        int kk = (int)(idx & 255);
        int j = (int)(idx >> 8);
        float lo = 0.f, hi = 0.f;
        if (j < VV) {
            lo = W2[(long)j * 512 + 2 * kk];
            hi = W2[(long)j * 512 + 2 * kk + 1];
        }
        Wb[idx] = packbf2(lo, hi);
    }
}

// fp32 transpose (MLP1): Wt[k][j] = A[j][k]
__global__ void transpose_cat(const float* __restrict__ A, int KA,
                              int J, int Jp, float* __restrict__ Wt) {
    long total = (long)KA * Jp;
    for (long idx = (long)blockIdx.x * 256 + threadIdx.x; idx < total;
         idx += (long)gridDim.x * 256) {
        int j = (int)(idx % Jp);
        int k = (int)(idx / Jp);
        Wt[idx] = (j < J) ? A[(long)j * KA + k] : 0.f;
    }
}

// ---------------------------------------------------------------------------
// MLP1: 8 rows/block, thread owns cols (2jp, 2jp+1); bf16-pair output.
// ---------------------------------------------------------------------------
__global__ void gemm_mlp1(const float* __restrict__ Wt,
                          const float* __restrict__ X,
                          const float* __restrict__ bias,
                          unsigned* __restrict__ outb) {
    __shared__ float xs[64 * 12];
    int m0 = blockIdx.x * 8;
    int lane = threadIdx.x & 63;
    int wv = threadIdx.x >> 6;
    int jp = wv * 64 + lane;
    float acc0[8], acc1[8];
#pragma unroll
    for (int q = 0; q < 8; q++) { acc0[q] = 0.f; acc1[q] = 0.f; }
    for (int kc = 0; kc < 1024; kc += 64) {
        __syncthreads();
        for (int idx = threadIdx.x; idx < 512; idx += 256) {
            int k = idx >> 3, n = idx & 7;
            xs[k * 12 + n] = X[(long)(m0 + n) * 1024 + kc + k];
        }
        __syncthreads();
        const float2* wpp = (const float2*)(Wt + (long)kc * 512) + jp;
#pragma unroll 4
        for (int k = 0; k < 64; k++) {
            float2 w = wpp[(long)k * 256];
            const float4* xv = (const float4*)(xs + k * 12);
            float4 x0 = xv[0], x1 = xv[1];
            acc0[0] += w.x * x0.x; acc0[1] += w.x * x0.y;
            acc0[2] += w.x * x0.z; acc0[3] += w.x * x0.w;
            acc0[4] += w.x * x1.x; acc0[5] += w.x * x1.y;
            acc0[6] += w.x * x1.z; acc0[7] += w.x * x1.w;
            acc1[0] += w.y * x0.x; acc1[1] += w.y * x0.y;
            acc1[2] += w.y * x0.z; acc1[3] += w.y * x0.w;
            acc1[4] += w.y * x1.x; acc1[5] += w.y * x1.y;
            acc1[6] += w.y * x1.z; acc1[7] += w.y * x1.w;
        }
    }
    float b0 = bias[2 * jp], b1 = bias[2 * jp + 1];
#pragma unroll
    for (int n = 0; n < 8; n++) {
        float v0 = tanhf(acc0[n] + b0);
        float v1 = tanhf(acc1[n] + b1);
        outb[(long)(m0 + n) * 256 + jp] = packbf2(v0, v1);
    }
}

// ---------------------------------------------------------------------------
// MLP2 via MFMA 16x16x32 bf16 (verified r15). Block = 32 rows x 256 cols.
// ---------------------------------------------------------------------------
__device__ __forceinline__ bf16x8 ldfrag(const unsigned short* p) {
    bf16x4 lo = *(const bf16x4*)p;
    bf16x4 hi = *(const bf16x4*)(p + 16);
    bf16x8 r;
    r[0] = lo[0]; r[1] = lo[1]; r[2] = lo[2]; r[3] = lo[3];
    r[4] = hi[0]; r[5] = hi[1]; r[6] = hi[2]; r[7] = hi[3];
    return r;
}

__global__ __launch_bounds__(256) void gemm_mlp2_mfma(
    const unsigned short* __restrict__ Wb2,   // [10240][512] bf16
    const unsigned short* __restrict__ Yb,    // [2080][512] bf16
    const float* __restrict__ bias,
    float* __restrict__ out) {
    int t = blockIdx.y;
    int m0 = t * 32;
    int l = threadIdx.x & 63, w = threadIdx.x >> 6;
    int colbase = blockIdx.x * 256 + w * 64;
    int r16 = l & 15, kq = l >> 4;
    f32x4 acc[2][4];
#pragma unroll
    for (int i = 0; i < 2; i++)
#pragma unroll
        for (int j = 0; j < 4; j++) acc[i][j] = (f32x4){0.f, 0.f, 0.f, 0.f};

    const unsigned short* a0p = Yb + (long)(m0 + r16) * 512 + kq * 4;
    const unsigned short* a1p = a0p + 16 * 512;
#pragma unroll 2
    for (int ks = 0; ks < 16; ks++) {
        int kb = ks * 32;
        bf16x8 a0 = ldfrag(a0p + kb);
        bf16x8 a1 = ldfrag(a1p + kb);
#pragma unroll
        for (int ct = 0; ct < 4; ct++) {
            const unsigned short* bp =
                Wb2 + (long)(colbase + ct * 16 + r16) * 512 + kb + kq * 4;
            bf16x8 bf = ldfrag(bp);
            acc[0][ct] = __builtin_amdgcn_mfma_f32_16x16x32_bf16(a0, bf, acc[0][ct], 0, 0, 0);
            acc[1][ct] = __builtin_amdgcn_mfma_f32_16x16x32_bf16(a1, bf, acc[1][ct], 0, 0, 0);
        }
    }
#pragma unroll
    for (int mi = 0; mi < 2; mi++)
#pragma unroll
        for (int ct = 0; ct < 4; ct++) {
            int col = colbase + ct * 16 + r16;
            if (col < VV) {
                float bv = bias[col];
#pragma unroll
                for (int r = 0; r < 4; r++) {
                    int nn = mi * 16 + kq * 4 + r;
                    out[((long)nn * TT + t) * VV + col] = acc[mi][ct][r] + bv;
                }
            }
        }
}

__global__ void loss_rows(const float* __restrict__ out, const int* __restrict__ tokens,
                          float* __restrict__ nll) {
    __shared__ float red[256];
    int row = blockIdx.x;
    int n = row / TT, t = row % TT;
    const float* y = out + (long)row * VV;
    int tid = threadIdx.x;
    float m = -1e30f;
    for (int v = tid; v < VV; v += 256) m = fmaxf(m, y[v]);
    red[tid] = m;
    __syncthreads();
    for (int s = 128; s > 0; s >>= 1) {
        if (tid < s) red[tid] = fmaxf(red[tid], red[tid + s]);
        __syncthreads();
    }
    m = red[0];
    __syncthreads();
    float sum = 0.f;
    for (int v = tid; v < VV; v += 256) sum += expf(y[v] - m);
    red[tid] = sum;
    __syncthreads();
    for (int s = 128; s > 0; s >>= 1) {
        if (tid < s) red[tid] += red[tid + s];
        __syncthreads();
    }
    if (tid == 0) {
        int target = (t < TO) ? tokens[n * TO + t] : EOS_ID;
        nll[row] = m + logf(red[0]) - y[target];
    }
}

__global__ void loss_final(const float* __restrict__ nll, float* __restrict__ out_loss) {
    __shared__ float red[256];
    int tid = threadIdx.x;
    float s = 0.f;
    for (int i = tid; i < NB * TT; i += 256) s += nll[i];
    red[tid] = s;
    __syncthreads();
    for (int k = 128; k > 0; k >>= 1) {
        if (tid < k) red[tid] += red[tid + k];
        __syncthreads();
    }
    if (tid == 0) *out_loss = red[0] / (float)(NB * TT);
}

extern "C" void kernel_launch(void* const* d_in, const int* in_sizes, int n_in,
                              void* d_out, int out_size, void* d_ws, size_t ws_size,
                              hipStream_t stream) {
    const int* padded   = (const int*)d_in[0];
    const float* enc    = (const float*)d_in[1];
    const float* emb    = (const float*)d_in[2];
    const float* W_ih0  = (const float*)d_in[3];
    const float* W_hh0  = (const float*)d_in[4];
    const float* b_ih0  = (const float*)d_in[5];
    const float* b_hh0  = (const float*)d_in[6];
    const float* W_ih_r = (const float*)d_in[7];
    const float* W_hh_r = (const float*)d_in[8];
    const float* b_ih_r = (const float*)d_in[9];
    const float* b_hh_r = (const float*)d_in[10];
    const float* W1     = (const float*)d_in[11];
    const float* b1     = (const float*)d_in[12];
    const float* W2     = (const float*)d_in[13];
    const float* b2     = (const float*)d_in[14];
    float* out = (float*)d_out;
    float* ws  = (float*)d_ws;

    // workspace (dwords)
    unsigned* Wtb0 = (unsigned*)ws;              // [384][4096]
    unsigned* Wtb1 = Wtb0 + 384 * 4096;          // [256][4096]
    unsigned* Wtb2 = Wtb1 + 256 * 4096;          // [256][4096]
    unsigned* Wb2u = Wtb2 + 256 * 4096;          // [10240][256] dwords (bf16 pairs)
    float* Wm1  = (float*)(Wb2u + 10240 * 256);  // [1024][512]
    float* hbuf = Wm1 + 1024 * 512;              // [2][3][32][512]
    float* mlpin= hbuf + 2 * 3 * NB * HH;        // [65][32][1024]
    unsigned* y1b = (unsigned*)(mlpin + (long)TT * NB * 1024);  // [2080][256] bf16 pairs
    float* pvec = (float*)(y1b + (long)TT * NB * 256);          // [32][8][512]
    float* pm   = pvec + 32 * 8 * 512;           // [32][8][2]
    float* nll  = pm + 512;                      // [2080]
    int*   flags= (int*)(nll + 2080);            // [8][32][16]

    hipMemsetAsync(hbuf, 0, (size_t)(2 * 3 * NB * HH) * sizeof(float), stream);
    hipMemsetAsync(flags, 0, 8 * 32 * 16 * sizeof(int), stream);

    transpose_cat<<<1024, 256, 0, stream>>>(W1, 1024, 512, 512, Wm1);
    transpose_lstm_q<<<2048, 256, 0, stream>>>(W_ih0, 1024, W_hh0, Wtb0);
    transpose_lstm_q<<<2048, 256, 0, stream>>>(W_ih_r, 512, W_hh_r, Wtb1);
    transpose_lstm_q<<<2048, 256, 0, stream>>>(W_ih_r + 2048 * 512, 512,
                                               W_hh_r + 2048 * 512, Wtb2);
    transpose_w2_bf<<<2048, 256, 0, stream>>>(W2, Wb2u);

    decode_loop<<<NBLK, 1024, 0, stream>>>(Wtb0, Wtb1, Wtb2, emb, padded, enc,
                                           b_ih0, b_hh0, b_ih_r, b_hh_r,
                                           hbuf, pvec, pm, mlpin, flags);

    gemm_mlp1<<<260, 256, 0, stream>>>(Wm1, mlpin, b1, y1b);
    gemm_mlp2_mfma<<<dim3(40, TT), 256, 0, stream>>>(
        (const unsigned short*)Wb2u, (const unsigned short*)y1b, b2, out);
    loss_rows<<<NB * TT, 256, 0, stream>>>(out, padded, nll);
    loss_final<<<1, 256, 0, stream>>>(nll, out + (long)NB * TT * VV);
}